// Round 8
// baseline (1358.607 us; speedup 1.0000x reference)
//
#include <hip/hip_runtime.h>

constexpr int DIN = 128, HIDF = 8;
constexpr int LOGD = 10, DPB = 1 << LOGD;   // dsts per bucket (1024)
constexpr int BE = 8192;                     // edges per partition block
constexpr int NBCAP = 256;                   // max buckets supported (N <= 256K); PB1 row stride

// ---------------- layer-1 projection: xp[N,8] = x[N,128] @ w[128,8] + b ----------------
__global__ __launch_bounds__(256) void k_proj1(
    const float* __restrict__ x, const float* __restrict__ w,
    const float* __restrict__ b, float* __restrict__ xp, int N)
{
  __shared__ float ws_[DIN * HIDF];
  __shared__ float xs[32 * 132];
  int t = threadIdx.x;
  ((float4*)ws_)[t] = ((const float4*)w)[t];
  int base = blockIdx.x * 32;
#pragma unroll
  for (int i = 0; i < 4; i++) {
    int f4 = t + i * 256;
    int nl = f4 >> 5;
    if (base + nl < N) {
      float4 v = ((const float4*)(x + (size_t)base * DIN))[f4];
      int col = (f4 & 31) << 2;
      *((float4*)&xs[nl * 132 + col]) = v;
    }
  }
  __syncthreads();
  int nl = t >> 3, j = t & 7;
  int n0 = base + nl;
  if (n0 >= N) return;
  float acc = b[j];
  const float* xr = &xs[nl * 132];
#pragma unroll 8
  for (int k = 0; k < DIN; k++) acc = fmaf(xr[k], ws_[k * HIDF + j], acc);
  xp[(size_t)n0 * HIDF + j] = acc;
}

// ---------------- per-node attention coefficients, layer 1 (H=2, D=4) ----------------
__global__ __launch_bounds__(256) void k_alpha1(
    const float* __restrict__ xp, int N,
    const float* __restrict__ p0, float* __restrict__ o0,
    const float* __restrict__ p1, float* __restrict__ o1,
    const float* __restrict__ p2, float* __restrict__ o2,
    const float* __restrict__ p3, float* __restrict__ o3)
{
  int n = blockIdx.x * blockDim.x + threadIdx.x;
  if (n >= N) return;
  float4 a4 = ((const float4*)xp)[(size_t)n * 2];
  float4 b4 = ((const float4*)xp)[(size_t)n * 2 + 1];
  float xv[8] = {a4.x, a4.y, a4.z, a4.w, b4.x, b4.y, b4.z, b4.w};
#define DOA(p, o)                                                     \
  if (p) {                                                            \
    float s0 = 0.f, s1 = 0.f;                                         \
    for (int d = 0; d < 4; d++) { s0 += xv[d] * p[d]; s1 += xv[4 + d] * p[4 + d]; } \
    ((float2*)o)[n] = make_float2(s0, s1);                            \
  }
  DOA(p0, o0) DOA(p1, o1) DOA(p2, o2) DOA(p3, o3)
#undef DOA
}

// ---------------- partition pass 1: per-(block,bucket) coarse histogram ----------------
// FIX (r7): PB1 row stride is NBCAP (not NBmax) — rows >= NBt stay inside this type's region.
__global__ __launch_bounds__(512) void k_bcount(
    const int* __restrict__ d0, const int* __restrict__ d1, const int* __restrict__ d2,
    int E, int nblocks, int* __restrict__ PB1)
{
  int ty = blockIdx.y;
  const int* dst = ty == 0 ? d0 : (ty == 1 ? d1 : d2);
  __shared__ int hist[NBCAP];
  int t = threadIdx.x;
  if (t < NBCAP) hist[t] = 0;
  __syncthreads();
  int blk = blockIdx.x;
  int e0 = blk * BE, e1 = min(E, e0 + BE);
  int qbase = e0 >> 2, nq = (e1 - e0) >> 2;
#pragma unroll
  for (int i = 0; i < 4; i++) {
    int q = i * 512 + t;
    if (q < nq) {
      int4 v = ((const int4*)dst)[qbase + q];
      atomicAdd(&hist[v.x >> LOGD], 1);
      atomicAdd(&hist[v.y >> LOGD], 1);
      atomicAdd(&hist[v.z >> LOGD], 1);
      atomicAdd(&hist[v.w >> LOGD], 1);
    }
  }
  __syncthreads();
  if (t < NBCAP) PB1[((size_t)(ty * NBCAP) + t) * nblocks + blk] = hist[t];
}

// ---------------- partition pass 2: scan per-bucket block counts (in place) ----------------
__global__ __launch_bounds__(512) void k_bscan(
    int* __restrict__ PB1, int* __restrict__ TOTS,
    int nblocks, int NBmax, int nb0, int nb1, int nb2)
{
  int ty = blockIdx.y;
  int NBt = ty == 0 ? nb0 : (ty == 1 ? nb1 : nb2);
  int bk = blockIdx.x;
  if (bk >= NBt) return;
  int* p = PB1 + ((size_t)(ty * NBCAP) + bk) * nblocks;
  int t = threadIdx.x;
  int v = (t < nblocks) ? p[t] : 0;
  int lane = t & 63, wv = t >> 6;
  int x = v;
#pragma unroll
  for (int o = 1; o < 64; o <<= 1) { int u = __shfl_up(x, o, 64); if (lane >= o) x += u; }
  __shared__ int ws[8];
  if (lane == 63) ws[wv] = x;
  __syncthreads();
  if (t == 0) { int s = 0; for (int k = 0; k < 8; k++) { int tmp = ws[k]; ws[k] = s; s += tmp; } }
  __syncthreads();
  int excl = x - v + ws[wv];
  if (t < nblocks) p[t] = excl;
  if (t == nblocks - 1) TOTS[ty * NBmax + bk] = excl + v;
}

// ---------------- partition pass 3: bucket start offsets (per type, within PART+ty*E) -------
__global__ __launch_bounds__(256) void k_bstart(
    const int* __restrict__ TOTS, int* __restrict__ BSTART,
    int NBmax, int nb0, int nb1, int nb2)
{
  int ty = blockIdx.x;
  int NBt = ty == 0 ? nb0 : (ty == 1 ? nb1 : nb2);
  int t = threadIdx.x;
  int v = (t < NBt) ? TOTS[ty * NBmax + t] : 0;
  int lane = t & 63, wv = t >> 6;
  int x = v;
#pragma unroll
  for (int o = 1; o < 64; o <<= 1) { int u = __shfl_up(x, o, 64); if (lane >= o) x += u; }
  __shared__ int ws[4];
  if (lane == 63) ws[wv] = x;
  __syncthreads();
  if (t == 0) { int s = 0; for (int k = 0; k < 4; k++) { int tmp = ws[k]; ws[k] = s; s += tmp; } }
  __syncthreads();
  int excl = x - v + ws[wv];
  int* bs = BSTART + (size_t)ty * (NBmax + 1);
  if (t < NBt) bs[t] = excl;
  if (t == NBt - 1) bs[NBt] = excl + v;
}

// ---------------- partition pass 4: LDS-staged bucket-partition of packed edges ----------------
__global__ __launch_bounds__(512) void k_bplace(
    const int* __restrict__ e0p, const int* __restrict__ e1p, const int* __restrict__ e2p,
    int E, int nblocks, int NBmax, int nb0, int nb1, int nb2,
    const int* __restrict__ PB1, const int* __restrict__ BSTART,
    int* __restrict__ PART)
{
  int ty = blockIdx.y;
  const int* src = ty == 0 ? e0p : (ty == 1 ? e1p : e2p);
  const int* dst = src + E;
  int NBt = ty == 0 ? nb0 : (ty == 1 ? nb1 : nb2);
  int* part = PART + (size_t)ty * E;
  __shared__ int hist[NBCAP];
  __shared__ int lscan[NBCAP + 1];
  __shared__ int bpref[NBCAP];
  __shared__ int bst[NBCAP];
  __shared__ int stage[BE];
  __shared__ int ws[8];
  int t = threadIdx.x;
  if (t < NBCAP) hist[t] = 0;
  __syncthreads();
  int blk = blockIdx.x;
  int e0 = blk * BE, e1 = min(E, e0 + BE);
  int cnt = e1 - e0;
  int qbase = e0 >> 2, nq = cnt >> 2;
  int dreg[16], sreg[16];
  unsigned short lr[16];
#pragma unroll
  for (int i = 0; i < 4; i++) {
    int q = i * 512 + t;
    if (q < nq) {
      int4 dq = ((const int4*)dst)[qbase + q];
      int4 sq = ((const int4*)src)[qbase + q];
      dreg[i * 4 + 0] = dq.x; dreg[i * 4 + 1] = dq.y;
      dreg[i * 4 + 2] = dq.z; dreg[i * 4 + 3] = dq.w;
      sreg[i * 4 + 0] = sq.x; sreg[i * 4 + 1] = sq.y;
      sreg[i * 4 + 2] = sq.z; sreg[i * 4 + 3] = sq.w;
#pragma unroll
      for (int k = 0; k < 4; k++)
        lr[i * 4 + k] = (unsigned short)atomicAdd(&hist[dreg[i * 4 + k] >> LOGD], 1);
    } else {
#pragma unroll
      for (int k = 0; k < 4; k++) dreg[i * 4 + k] = -1;
    }
  }
  __syncthreads();
  // exclusive scan of 256 hist bins
  {
    int v = (t < NBCAP) ? hist[t] : 0;
    int lane = t & 63, wv = t >> 6;
    int x = v;
#pragma unroll
    for (int o = 1; o < 64; o <<= 1) { int u = __shfl_up(x, o, 64); if (lane >= o) x += u; }
    if (lane == 63) ws[wv] = x;
    __syncthreads();
    if (t == 0) { int s = 0; for (int k = 0; k < 8; k++) { int tmp = ws[k]; ws[k] = s; s += tmp; } }
    __syncthreads();
    int excl = x - v + ws[wv];
    if (t < NBCAP) lscan[t] = excl;
    if (t == NBCAP - 1) lscan[NBCAP] = excl + v;
  }
  if (t < NBt) {
    bpref[t] = PB1[((size_t)(ty * NBCAP) + t) * nblocks + blk];
    bst[t] = BSTART[(size_t)ty * (NBmax + 1) + t];
  }
  __syncthreads();
#pragma unroll
  for (int i = 0; i < 16; i++) {
    int d = dreg[i];
    if (d >= 0) {
      int bk = d >> LOGD;
      stage[lscan[bk] + lr[i]] = (sreg[i] << LOGD) | (d & (DPB - 1));
    }
  }
  __syncthreads();
  for (int j = t; j < cnt; j += 512) {
    int lo = 0, hi = NBt - 1;
    while (lo < hi) { int mid = (lo + hi + 1) >> 1; if (lscan[mid] <= j) lo = mid; else hi = mid - 1; }
    part[bst[lo] + bpref[lo] + (j - lscan[lo])] = stage[j];
  }
}

// ---------------- layer-1 per-bucket softmax-aggregate (H=2, D=4) ----------------
__global__ __launch_bounds__(256) void k_aggr1(
    const int* __restrict__ PART, const int* __restrict__ BSTART, int NBmax, int E,
    const float* __restrict__ as0, const float* __restrict__ ad0,
    const float* __restrict__ x0, float* __restrict__ o0, int n0,
    const float* __restrict__ as1, const float* __restrict__ ad1,
    const float* __restrict__ x1, float* __restrict__ o1, int n1,
    const float* __restrict__ as2, const float* __restrict__ ad2,
    const float* __restrict__ x2, float* __restrict__ o2, int n2)
{
  int ty = blockIdx.y;
  const float* as_ = ty == 0 ? as0 : (ty == 1 ? as1 : as2);
  const float* ad_ = ty == 0 ? ad0 : (ty == 1 ? ad1 : ad2);
  const float* xps = ty == 0 ? x0 : (ty == 1 ? x1 : x2);
  float* out = ty == 0 ? o0 : (ty == 1 ? o1 : o2);
  int Nt = ty == 0 ? n0 : (ty == 1 ? n1 : n2);
  const int* part = PART + (size_t)ty * E;
  int bk = blockIdx.x;
  int d0 = bk << LOGD;
  if (d0 >= Nt) return;
  int nd = min(DPB, Nt - d0);
  __shared__ float acc[DPB * 11];          // 8 acc + 2 denom, stride 11 (bank-spread)
  __shared__ float2 adv[DPB];
  int t = threadIdx.x;
  for (int i = t; i < DPB * 11; i += 256) acc[i] = 0.f;
  for (int i = t; i < nd; i += 256) adv[i] = ((const float2*)ad_)[d0 + i];
  __syncthreads();
  const int* bs = BSTART + (size_t)ty * (NBmax + 1);
  int s0 = bs[bk], s1 = bs[bk + 1];
  for (int j = s0 + t; j < s1; j += 256) {
    int v = part[j];
    int s = v >> LOGD, dl = v & (DPB - 1);
    float2 av = ((const float2*)as_)[s];
    float a0 = av.x + adv[dl].x; a0 = a0 > 0.f ? a0 : 0.2f * a0;
    float a1 = av.y + adv[dl].y; a1 = a1 > 0.f ? a1 : 0.2f * a1;
    float e0 = __expf(a0), e1 = __expf(a1);
    float4 xa = ((const float4*)xps)[(size_t)s * 2];
    float4 xb = ((const float4*)xps)[(size_t)s * 2 + 1];
    float* A = &acc[dl * 11];
    atomicAdd(A + 0, e0 * xa.x); atomicAdd(A + 1, e0 * xa.y);
    atomicAdd(A + 2, e0 * xa.z); atomicAdd(A + 3, e0 * xa.w);
    atomicAdd(A + 4, e1 * xb.x); atomicAdd(A + 5, e1 * xb.y);
    atomicAdd(A + 6, e1 * xb.z); atomicAdd(A + 7, e1 * xb.w);
    atomicAdd(A + 8, e0); atomicAdd(A + 9, e1);
  }
  __syncthreads();
  for (int dl = t; dl < nd; dl += 256) {
    float* A = &acc[dl * 11];
    float r0 = 1.f / (A[8] + 1e-16f), r1 = 1.f / (A[9] + 1e-16f);
    float4 q0 = make_float4(fmaxf(A[0] * r0, 0.f), fmaxf(A[1] * r0, 0.f),
                            fmaxf(A[2] * r0, 0.f), fmaxf(A[3] * r0, 0.f));
    float4 q1 = make_float4(fmaxf(A[4] * r1, 0.f), fmaxf(A[5] * r1, 0.f),
                            fmaxf(A[6] * r1, 0.f), fmaxf(A[7] * r1, 0.f));
    ((float4*)out)[(size_t)(d0 + dl) * 2] = q0;
    ((float4*)out)[(size_t)(d0 + dl) * 2 + 1] = q1;
  }
}

// ---------------- layer-2 per-bucket softmax-aggregate (H=1, F=7) ----------------
__global__ __launch_bounds__(256) void k_aggr2(
    const int* __restrict__ PART, const int* __restrict__ BSTART, int NBmax, int E,
    int ti0, int ti1,
    const float* __restrict__ as0, const float* __restrict__ ad0,
    const float* __restrict__ x0, float* __restrict__ o0,
    const float* __restrict__ as1, const float* __restrict__ ad1,
    const float* __restrict__ x1, float* __restrict__ o1, int N)
{
  int zz = blockIdx.y;
  int ty = zz == 0 ? ti0 : ti1;
  const float* as_ = zz == 0 ? as0 : as1;
  const float* ad_ = zz == 0 ? ad0 : ad1;
  const float* xps = zz == 0 ? x0 : x1;
  float* out = zz == 0 ? o0 : o1;
  const int* part = PART + (size_t)ty * E;
  int bk = blockIdx.x;
  int d0 = bk << LOGD;
  if (d0 >= N) return;
  int nd = min(DPB, N - d0);
  __shared__ float acc[DPB * 9];           // 7 acc + 1 denom, stride 9
  __shared__ float adv[DPB];
  int t = threadIdx.x;
  for (int i = t; i < DPB * 9; i += 256) acc[i] = 0.f;
  for (int i = t; i < nd; i += 256) adv[i] = ad_[d0 + i];
  __syncthreads();
  const int* bs = BSTART + (size_t)ty * (NBmax + 1);
  int s0 = bs[bk], s1 = bs[bk + 1];
  for (int j = s0 + t; j < s1; j += 256) {
    int v = part[j];
    int s = v >> LOGD, dl = v & (DPB - 1);
    float a = as_[s] + adv[dl]; a = a > 0.f ? a : 0.2f * a;
    float ex = __expf(a);
    float4 xa = ((const float4*)xps)[(size_t)s * 2];
    float4 xb = ((const float4*)xps)[(size_t)s * 2 + 1];
    float* A = &acc[dl * 9];
    atomicAdd(A + 0, ex * xa.x); atomicAdd(A + 1, ex * xa.y);
    atomicAdd(A + 2, ex * xa.z); atomicAdd(A + 3, ex * xa.w);
    atomicAdd(A + 4, ex * xb.x); atomicAdd(A + 5, ex * xb.y);
    atomicAdd(A + 6, ex * xb.z); atomicAdd(A + 7, ex);
  }
  __syncthreads();
  for (int dl = t; dl < nd; dl += 256) {
    float* A = &acc[dl * 9];
    float r = 1.f / (A[7] + 1e-16f);
    float4 q0 = make_float4(fmaxf(A[0] * r, 0.f), fmaxf(A[1] * r, 0.f),
                            fmaxf(A[2] * r, 0.f), fmaxf(A[3] * r, 0.f));
    float4 q1 = make_float4(fmaxf(A[4] * r, 0.f), fmaxf(A[5] * r, 0.f),
                            fmaxf(A[6] * r, 0.f), 0.f);
    ((float4*)out)[(size_t)(d0 + dl) * 2] = q0;
    ((float4*)out)[(size_t)(d0 + dl) * 2 + 1] = q1;
  }
}

// ---------------- semantic-attention reduction ----------------
__global__ __launch_bounds__(256) void k_red(
    const float* __restrict__ h, int N, int F,
    const float* __restrict__ kw, const float* __restrict__ kb,
    float* __restrict__ red)
{
  __shared__ float kws[64], kbs[8];
  __shared__ float sm[256 * 8];
  int t = threadIdx.x;
  if (t < F * F) kws[t] = kw[t];
  if (t < F) kbs[t] = kb[t];
  __syncthreads();
  float acc[8] = {0, 0, 0, 0, 0, 0, 0, 0};
  for (int n = blockIdx.x * 256 + t; n < N; n += gridDim.x * 256) {
    const float* row = h + (size_t)n * 8;
    float xv[8];
    for (int k = 0; k < F; k++) xv[k] = row[k];
    for (int f = 0; f < F; f++) {
      float s = kbs[f];
      for (int k = 0; k < F; k++) s += xv[k] * kws[k * F + f];
      acc[f] += tanhf(s);
    }
  }
  for (int f = 0; f < 8; f++) sm[t * 8 + f] = (f < F) ? acc[f] : 0.f;
  __syncthreads();
  for (int s2 = 128; s2 > 0; s2 >>= 1) {
    if (t < s2)
      for (int f = 0; f < 8; f++) sm[t * 8 + f] += sm[(t + s2) * 8 + f];
    __syncthreads();
  }
  if (t < F) atomicAdd(&red[t], sm[t]);
}

// ---------------- semantic attention weights (tiny) ----------------
__global__ void k_attn(const float* __restrict__ red, const float* __restrict__ q,
                       int T, int F, float invN, float* __restrict__ attn)
{
  if (threadIdx.x != 0 || blockIdx.x != 0) return;
  float v[4]; float m = -1e30f;
  for (int t2 = 0; t2 < T; t2++) {
    float s = 0.f;
    for (int f = 0; f < F; f++) s += q[f] * red[t2 * F + f];
    s *= invN;
    v[t2] = s; m = fmaxf(m, s);
  }
  float sum = 0.f;
  for (int t2 = 0; t2 < T; t2++) { v[t2] = __expf(v[t2] - m); sum += v[t2]; }
  for (int t2 = 0; t2 < T; t2++) attn[t2] = v[t2] / sum;
}

// ---------- layer-2 projection with fused semantic combine (+relu) + fused alpha2 ----------
__global__ __launch_bounds__(256) void k_proj2(
    const float* __restrict__ h0, const float* __restrict__ h1,
    const float* __restrict__ attn, int N,
    const float* __restrict__ w, const float* __restrict__ b,
    float* __restrict__ xp2,
    const float* __restrict__ pa0, float* __restrict__ oa0,
    const float* __restrict__ pa1, float* __restrict__ oa1,
    const float* __restrict__ pa2, float* __restrict__ oa2)
{
  int n = blockIdx.x * blockDim.x + threadIdx.x;
  if (n >= N) return;
  float a0 = 1.f, a1 = 0.f;
  if (attn) { a0 = attn[0]; a1 = attn[1]; }
  float4 u0 = ((const float4*)h0)[(size_t)n * 2];
  float4 u1 = ((const float4*)h0)[(size_t)n * 2 + 1];
  float xv[8] = {u0.x, u0.y, u0.z, u0.w, u1.x, u1.y, u1.z, u1.w};
  if (h1) {
    float4 v0 = ((const float4*)h1)[(size_t)n * 2];
    float4 v1 = ((const float4*)h1)[(size_t)n * 2 + 1];
    float yv[8] = {v0.x, v0.y, v0.z, v0.w, v1.x, v1.y, v1.z, v1.w};
    for (int j = 0; j < 8; j++) xv[j] = a0 * xv[j] + a1 * yv[j];
  }
  for (int j = 0; j < 8; j++) xv[j] = fmaxf(xv[j], 0.f);
  float y[7];
  for (int j = 0; j < 7; j++) y[j] = b[j];
  for (int k = 0; k < 8; k++) {
    float xk = xv[k];
    for (int j = 0; j < 7; j++) y[j] += xk * w[k * 7 + j];
  }
  ((float4*)xp2)[(size_t)n * 2] = make_float4(y[0], y[1], y[2], y[3]);
  ((float4*)xp2)[(size_t)n * 2 + 1] = make_float4(y[4], y[5], y[6], 0.f);
#define DOA2(p, o)                                      \
  if (p) {                                              \
    float s = 0.f;                                      \
    for (int j = 0; j < 7; j++) s += y[j] * p[j];       \
    o[n] = s;                                           \
  }
  DOA2(pa0, oa0) DOA2(pa1, oa1) DOA2(pa2, oa2)
#undef DOA2
}

// ---------------- final combine + log_softmax ----------------
__global__ __launch_bounds__(256) void k_final(
    const float* __restrict__ h0, const float* __restrict__ h1,
    const float* __restrict__ attn, float* __restrict__ out, int N)
{
  int n = blockIdx.x * blockDim.x + threadIdx.x;
  if (n >= N) return;
  float a0 = attn[0], a1 = attn[1];
  const float* r0 = h0 + (size_t)n * 8;
  const float* r1 = h1 + (size_t)n * 8;
  float v[7]; float m = -1e30f;
  for (int c = 0; c < 7; c++) { float t = a0 * r0[c] + a1 * r1[c]; v[c] = t; m = fmaxf(m, t); }
  float sum = 0.f;
  for (int c = 0; c < 7; c++) sum += __expf(v[c] - m);
  float lse = m + logf(sum);
  for (int c = 0; c < 7; c++) out[(size_t)n * 7 + c] = v[c] - lse;
}

extern "C" void kernel_launch(void* const* d_in, const int* in_sizes, int n_in,
                              void* d_out, int out_size, void* d_ws, size_t ws_size,
                              hipStream_t stream)
{
  const float* x_p  = (const float*)d_in[0];
  const float* x_a  = (const float*)d_in[1];
  const int*   eipp = (const int*)d_in[2];
  const int*   eipa = (const int*)d_in[3];
  const int*   eiap = (const int*)d_in[4];
  const float* w1p  = (const float*)d_in[5];
  const float* b1p  = (const float*)d_in[6];
  const float* w1a  = (const float*)d_in[7];
  const float* b1a  = (const float*)d_in[8];
  const float* as1pp = (const float*)d_in[9];
  const float* ad1pp = (const float*)d_in[10];
  const float* as1pa = (const float*)d_in[11];
  const float* ad1pa = (const float*)d_in[12];
  const float* as1ap = (const float*)d_in[13];
  const float* ad1ap = (const float*)d_in[14];
  const float* kw1 = (const float*)d_in[15];
  const float* kb1 = (const float*)d_in[16];
  const float* q1  = (const float*)d_in[17];
  const float* w2p = (const float*)d_in[18];
  const float* b2p = (const float*)d_in[19];
  const float* w2a = (const float*)d_in[20];
  const float* b2a = (const float*)d_in[21];
  const float* as2pp = (const float*)d_in[22];
  const float* ad2pp = (const float*)d_in[23];
  // d_in[24]=as2pa, d_in[25]=ad2pa unused: pa edges only feed author nodes,
  // and author layer-2 output is dead (final output is papers only).
  const float* as2ap = (const float*)d_in[26];
  const float* ad2ap = (const float*)d_in[27];
  const float* kw2 = (const float*)d_in[28];
  const float* kb2 = (const float*)d_in[29];
  const float* q2  = (const float*)d_in[30];

  const int NP = in_sizes[0] / DIN;
  const int NA = in_sizes[1] / DIN;
  const int E  = in_sizes[2] / 2;
  (void)n_in; (void)out_size; (void)ws_size;

  const int nblocks = (E + BE - 1) / BE;
  const int NBp = (NP + DPB - 1) >> LOGD;
  const int NBa = (NA + DPB - 1) >> LOGD;
  const int NBmax = NBp > NBa ? NBp : NBa;

  float* w = (float*)d_ws;
  size_t off_ = 0;
  auto A = [&](size_t n) { float* p = w + off_; off_ += (n + 3) & ~(size_t)3; return p; };
  float* XP_P1 = A((size_t)NP * 8);   // reused as XP2_P
  float* XP_A1 = A((size_t)NA * 8);   // reused as XP2_A
  float* AS_PP = A((size_t)NP * 2);   // reused as A2SPP
  float* AD_PP = A((size_t)NP * 2);   // reused as A2DPP
  float* AS_PA = A((size_t)NP * 2);   // reused as A2DAP
  float* AD_PA = A((size_t)NA * 2);   // reused as A2SAP
  float* AS_AP = A((size_t)NA * 2);
  float* AD_AP = A((size_t)NP * 2);
  float* O_PP  = A((size_t)NP * 8);   // reused as O2PP
  float* O_PA  = A((size_t)NA * 8);
  float* O_AP  = A((size_t)NP * 8);   // reused as O2AP
  float* ATT1  = A(2);
  float* ATT2  = A(2);
  float* RED1  = A(16);
  float* RED2  = A(16);
  int* PART   = (int*)A((size_t)3 * E);                    // per-type regions PART + ty*E
  int* PB1    = (int*)A((size_t)3 * NBCAP * nblocks);      // row stride NBCAP (r7 fix)
  int* TOTS   = (int*)A((size_t)3 * NBmax);
  int* BSTART = (int*)A((size_t)3 * (NBmax + 1));

  float* XP2_P = XP_P1;
  float* XP2_A = XP_A1;
  float* A2SPP = AS_PP;
  float* A2DPP = AD_PP;
  float* A2DAP = AS_PA;
  float* A2SAP = AD_PA;
  float* O2PP  = O_PP;
  float* O2AP  = O_AP;

  hipMemsetAsync(RED1, 0, 32 * sizeof(float), stream);  // RED1+RED2 contiguous

  dim3 B(256);
  int nbP = (NP + 255) / 256, nbA = (NA + 255) / 256;

  // layer 1 projections + per-node alphas
  k_proj1<<<(NP + 31) / 32, B, 0, stream>>>(x_p, w1p, b1p, XP_P1, NP);
  k_proj1<<<(NA + 31) / 32, B, 0, stream>>>(x_a, w1a, b1a, XP_A1, NA);
  k_alpha1<<<nbP, B, 0, stream>>>(XP_P1, NP,
      as1pp, AS_PP, ad1pp, AD_PP, as1pa, AS_PA, ad1ap, AD_AP);
  k_alpha1<<<nbA, B, 0, stream>>>(XP_A1, NA,
      ad1pa, AD_PA, as1ap, AS_AP, nullptr, nullptr, nullptr, nullptr);

  // bucket partition for all 3 edge types (type order: pp, pa, ap; bucket = dst >> 10)
  k_bcount<<<dim3(nblocks, 3), dim3(512), 0, stream>>>(
      eipp + E, eipa + E, eiap + E, E, nblocks, PB1);
  k_bscan<<<dim3(NBmax, 3), dim3(512), 0, stream>>>(
      PB1, TOTS, nblocks, NBmax, NBp, NBa, NBp);
  k_bstart<<<3, B, 0, stream>>>(TOTS, BSTART, NBmax, NBp, NBa, NBp);
  k_bplace<<<dim3(nblocks, 3), dim3(512), 0, stream>>>(
      eipp, eipa, eiap, E, nblocks, NBmax, NBp, NBa, NBp, PB1, BSTART, PART);

  // layer-1 per-bucket aggregation (all 3 types)
  k_aggr1<<<dim3(NBmax, 3), B, 0, stream>>>(
      PART, BSTART, NBmax, E,
      AS_PP, AD_PP, XP_P1, O_PP, NP,
      AS_PA, AD_PA, XP_P1, O_PA, NA,
      AS_AP, AD_AP, XP_A1, O_AP, NP);

  // layer 1 semantic attention (paper: T=2; author: T=1 -> O_PA passes through)
  k_red<<<256, B, 0, stream>>>(O_PP, NP, 8, kw1, kb1, RED1);
  k_red<<<256, B, 0, stream>>>(O_AP, NP, 8, kw1, kb1, RED1 + 8);
  k_attn<<<1, 1, 0, stream>>>(RED1, q1, 2, 8, 1.0f / NP, ATT1);

  // layer 2 projections (paper: fused semantic combine; author: passthrough) + alphas
  k_proj2<<<nbP, B, 0, stream>>>(O_PP, O_AP, ATT1, NP, w2p, b2p, XP2_P,
      as2pp, A2SPP, ad2pp, A2DPP, ad2ap, A2DAP);
  k_proj2<<<nbA, B, 0, stream>>>(O_PA, nullptr, nullptr, NA, w2a, b2a, XP2_A,
      as2ap, A2SAP, nullptr, nullptr, nullptr, nullptr);

  // layer-2 per-bucket aggregation (pp and ap; author layer-2 output is dead)
  k_aggr2<<<dim3(NBp, 2), B, 0, stream>>>(
      PART, BSTART, NBmax, E, 0, 2,
      A2SPP, A2DPP, XP2_P, O2PP,
      A2SAP, A2DAP, XP2_A, O2AP, NP);

  // layer 2 semantic attention + final log_softmax
  k_red<<<256, B, 0, stream>>>(O2PP, NP, 7, kw2, kb2, RED2);
  k_red<<<256, B, 0, stream>>>(O2AP, NP, 7, kw2, kb2, RED2 + 7);
  k_attn<<<1, 1, 0, stream>>>(RED2, q2, 2, 7, 1.0f / NP, ATT2);
  k_final<<<nbP, B, 0, stream>>>(O2PP, O2AP, ATT2, (float*)d_out, NP);
}

// Round 9
// 1054.371 us; speedup vs baseline: 1.2885x; 1.2885x over previous
//
#include <hip/hip_runtime.h>

constexpr int DIN = 128, HIDF = 8;
constexpr int LOGD = 8, DPB = 1 << LOGD;    // dsts per bucket (256)
constexpr int BE = 8192;                     // edges per partition block
constexpr int NBCAP = 512;                   // max buckets (N <= 128K); PB1 row stride

// ---------------- layer-1 projection: xp[N,8] = x[N,128] @ w[128,8] + b ----------------
__global__ __launch_bounds__(256) void k_proj1(
    const float* __restrict__ x, const float* __restrict__ w,
    const float* __restrict__ b, float* __restrict__ xp, int N)
{
  __shared__ float ws_[DIN * HIDF];
  __shared__ float xs[32 * 132];
  int t = threadIdx.x;
  ((float4*)ws_)[t] = ((const float4*)w)[t];
  int base = blockIdx.x * 32;
#pragma unroll
  for (int i = 0; i < 4; i++) {
    int f4 = t + i * 256;
    int nl = f4 >> 5;
    if (base + nl < N) {
      float4 v = ((const float4*)(x + (size_t)base * DIN))[f4];
      int col = (f4 & 31) << 2;
      *((float4*)&xs[nl * 132 + col]) = v;
    }
  }
  __syncthreads();
  int nl = t >> 3, j = t & 7;
  int n0 = base + nl;
  if (n0 >= N) return;
  float acc = b[j];
  const float* xr = &xs[nl * 132];
#pragma unroll 8
  for (int k = 0; k < DIN; k++) acc = fmaf(xr[k], ws_[k * HIDF + j], acc);
  xp[(size_t)n0 * HIDF + j] = acc;
}

// ---------------- per-node attention coefficients, layer 1 (H=2, D=4) ----------------
__global__ __launch_bounds__(256) void k_alpha1(
    const float* __restrict__ xp, int N,
    const float* __restrict__ p0, float* __restrict__ o0,
    const float* __restrict__ p1, float* __restrict__ o1,
    const float* __restrict__ p2, float* __restrict__ o2,
    const float* __restrict__ p3, float* __restrict__ o3)
{
  int n = blockIdx.x * blockDim.x + threadIdx.x;
  if (n >= N) return;
  float4 a4 = ((const float4*)xp)[(size_t)n * 2];
  float4 b4 = ((const float4*)xp)[(size_t)n * 2 + 1];
  float xv[8] = {a4.x, a4.y, a4.z, a4.w, b4.x, b4.y, b4.z, b4.w};
#define DOA(p, o)                                                     \
  if (p) {                                                            \
    float s0 = 0.f, s1 = 0.f;                                         \
    for (int d = 0; d < 4; d++) { s0 += xv[d] * p[d]; s1 += xv[4 + d] * p[4 + d]; } \
    ((float2*)o)[n] = make_float2(s0, s1);                            \
  }
  DOA(p0, o0) DOA(p1, o1) DOA(p2, o2) DOA(p3, o3)
#undef DOA
}

// ---------------- partition pass 1: per-(block,bucket) coarse histogram ----------------
__global__ __launch_bounds__(512) void k_bcount(
    const int* __restrict__ d0, const int* __restrict__ d1, const int* __restrict__ d2,
    int E, int nblocks, int* __restrict__ PB1)
{
  int ty = blockIdx.y;
  const int* dst = ty == 0 ? d0 : (ty == 1 ? d1 : d2);
  __shared__ int hist[NBCAP];
  int t = threadIdx.x;
  hist[t] = 0;                         // blockDim == NBCAP == 512
  __syncthreads();
  int blk = blockIdx.x;
  int e0 = blk * BE, e1 = min(E, e0 + BE);
  int qbase = e0 >> 2, nq = (e1 - e0) >> 2;
#pragma unroll
  for (int i = 0; i < 4; i++) {
    int q = i * 512 + t;
    if (q < nq) {
      int4 v = ((const int4*)dst)[qbase + q];
      atomicAdd(&hist[v.x >> LOGD], 1);
      atomicAdd(&hist[v.y >> LOGD], 1);
      atomicAdd(&hist[v.z >> LOGD], 1);
      atomicAdd(&hist[v.w >> LOGD], 1);
    }
  }
  __syncthreads();
  PB1[((size_t)(ty * NBCAP) + t) * nblocks + blk] = hist[t];
}

// ---------------- partition pass 2: scan per-bucket block counts (in place) ----------------
__global__ __launch_bounds__(512) void k_bscan(
    int* __restrict__ PB1, int* __restrict__ TOTS,
    int nblocks, int NBmax, int nb0, int nb1, int nb2)
{
  int ty = blockIdx.y;
  int NBt = ty == 0 ? nb0 : (ty == 1 ? nb1 : nb2);
  int bk = blockIdx.x;
  if (bk >= NBt) return;
  int* p = PB1 + ((size_t)(ty * NBCAP) + bk) * nblocks;
  int t = threadIdx.x;
  int v = (t < nblocks) ? p[t] : 0;
  int lane = t & 63, wv = t >> 6;
  int x = v;
#pragma unroll
  for (int o = 1; o < 64; o <<= 1) { int u = __shfl_up(x, o, 64); if (lane >= o) x += u; }
  __shared__ int ws[8];
  if (lane == 63) ws[wv] = x;
  __syncthreads();
  if (t == 0) { int s = 0; for (int k = 0; k < 8; k++) { int tmp = ws[k]; ws[k] = s; s += tmp; } }
  __syncthreads();
  int excl = x - v + ws[wv];
  if (t < nblocks) p[t] = excl;
  if (t == nblocks - 1) TOTS[ty * NBmax + bk] = excl + v;
}

// ---------------- partition pass 3: bucket start offsets (per type, within PART+ty*E) -------
__global__ __launch_bounds__(512) void k_bstart(
    const int* __restrict__ TOTS, int* __restrict__ BSTART,
    int NBmax, int nb0, int nb1, int nb2)
{
  int ty = blockIdx.x;
  int NBt = ty == 0 ? nb0 : (ty == 1 ? nb1 : nb2);
  int t = threadIdx.x;
  int v = (t < NBt) ? TOTS[ty * NBmax + t] : 0;
  int lane = t & 63, wv = t >> 6;
  int x = v;
#pragma unroll
  for (int o = 1; o < 64; o <<= 1) { int u = __shfl_up(x, o, 64); if (lane >= o) x += u; }
  __shared__ int ws[8];
  if (lane == 63) ws[wv] = x;
  __syncthreads();
  if (t == 0) { int s = 0; for (int k = 0; k < 8; k++) { int tmp = ws[k]; ws[k] = s; s += tmp; } }
  __syncthreads();
  int excl = x - v + ws[wv];
  int* bs = BSTART + (size_t)ty * (NBmax + 1);
  if (t < NBt) bs[t] = excl;
  if (t == NBt - 1) bs[NBt] = excl + v;
}

// ---------------- partition pass 4: LDS-staged bucket-partition of packed edges ----------------
__global__ __launch_bounds__(512) void k_bplace(
    const int* __restrict__ e0p, const int* __restrict__ e1p, const int* __restrict__ e2p,
    int E, int nblocks, int NBmax, int nb0, int nb1, int nb2,
    const int* __restrict__ PB1, const int* __restrict__ BSTART,
    int* __restrict__ PART)
{
  int ty = blockIdx.y;
  const int* src = ty == 0 ? e0p : (ty == 1 ? e1p : e2p);
  const int* dst = src + E;
  int NBt = ty == 0 ? nb0 : (ty == 1 ? nb1 : nb2);
  int* part = PART + (size_t)ty * E;
  __shared__ int hist[NBCAP];
  __shared__ int lscan[NBCAP + 1];
  __shared__ int bpref[NBCAP];
  __shared__ int bst[NBCAP];
  __shared__ int stage[BE];
  __shared__ int ws[8];
  int t = threadIdx.x;
  hist[t] = 0;
  __syncthreads();
  int blk = blockIdx.x;
  int e0 = blk * BE, e1 = min(E, e0 + BE);
  int cnt = e1 - e0;
  int qbase = e0 >> 2, nq = cnt >> 2;
  int dreg[16], sreg[16];
  unsigned short lr[16];
#pragma unroll
  for (int i = 0; i < 4; i++) {
    int q = i * 512 + t;
    if (q < nq) {
      int4 dq = ((const int4*)dst)[qbase + q];
      int4 sq = ((const int4*)src)[qbase + q];
      dreg[i * 4 + 0] = dq.x; dreg[i * 4 + 1] = dq.y;
      dreg[i * 4 + 2] = dq.z; dreg[i * 4 + 3] = dq.w;
      sreg[i * 4 + 0] = sq.x; sreg[i * 4 + 1] = sq.y;
      sreg[i * 4 + 2] = sq.z; sreg[i * 4 + 3] = sq.w;
#pragma unroll
      for (int k = 0; k < 4; k++)
        lr[i * 4 + k] = (unsigned short)atomicAdd(&hist[dreg[i * 4 + k] >> LOGD], 1);
    } else {
#pragma unroll
      for (int k = 0; k < 4; k++) dreg[i * 4 + k] = -1;
    }
  }
  __syncthreads();
  // exclusive scan of 512 hist bins (512 threads, 8 wave-groups)
  {
    int v = hist[t];
    int lane = t & 63, wv = t >> 6;
    int x = v;
#pragma unroll
    for (int o = 1; o < 64; o <<= 1) { int u = __shfl_up(x, o, 64); if (lane >= o) x += u; }
    if (lane == 63) ws[wv] = x;
    __syncthreads();
    if (t == 0) { int s = 0; for (int k = 0; k < 8; k++) { int tmp = ws[k]; ws[k] = s; s += tmp; } }
    __syncthreads();
    int excl = x - v + ws[wv];
    lscan[t] = excl;
    if (t == NBCAP - 1) lscan[NBCAP] = excl + v;
  }
  if (t < NBt) {
    bpref[t] = PB1[((size_t)(ty * NBCAP) + t) * nblocks + blk];
    bst[t] = BSTART[(size_t)ty * (NBmax + 1) + t];
  }
  __syncthreads();
#pragma unroll
  for (int i = 0; i < 16; i++) {
    int d = dreg[i];
    if (d >= 0) {
      int bk = d >> LOGD;
      stage[lscan[bk] + lr[i]] = (sreg[i] << LOGD) | (d & (DPB - 1));
    }
  }
  __syncthreads();
  for (int j = t; j < cnt; j += 512) {
    int lo = 0, hi = NBt - 1;
    while (lo < hi) { int mid = (lo + hi + 1) >> 1; if (lscan[mid] <= j) lo = mid; else hi = mid - 1; }
    part[bst[lo] + bpref[lo] + (j - lscan[lo])] = stage[j];
  }
}

// ---------------- layer-1 per-bucket softmax-aggregate (H=2, D=4) ----------------
__global__ __launch_bounds__(256) void k_aggr1(
    const int* __restrict__ PART, const int* __restrict__ BSTART, int NBmax, int E,
    const float* __restrict__ as0, const float* __restrict__ ad0,
    const float* __restrict__ x0, float* __restrict__ o0, int n0,
    const float* __restrict__ as1, const float* __restrict__ ad1,
    const float* __restrict__ x1, float* __restrict__ o1, int n1,
    const float* __restrict__ as2, const float* __restrict__ ad2,
    const float* __restrict__ x2, float* __restrict__ o2, int n2)
{
  int ty = blockIdx.y;
  const float* as_ = ty == 0 ? as0 : (ty == 1 ? as1 : as2);
  const float* ad_ = ty == 0 ? ad0 : (ty == 1 ? ad1 : ad2);
  const float* xps = ty == 0 ? x0 : (ty == 1 ? x1 : x2);
  float* out = ty == 0 ? o0 : (ty == 1 ? o1 : o2);
  int Nt = ty == 0 ? n0 : (ty == 1 ? n1 : n2);
  const int* part = PART + (size_t)ty * E;
  int bk = blockIdx.x;
  int d0 = bk << LOGD;
  if (d0 >= Nt) return;
  int nd = min(DPB, Nt - d0);
  __shared__ float acc[DPB * 11];          // 8 acc + 2 denom, stride 11 (bank-spread)
  __shared__ float2 adv[DPB];
  int t = threadIdx.x;
  for (int i = t; i < DPB * 11; i += 256) acc[i] = 0.f;
  for (int i = t; i < nd; i += 256) adv[i] = ((const float2*)ad_)[d0 + i];
  __syncthreads();
  const int* bs = BSTART + (size_t)ty * (NBmax + 1);
  int s0 = bs[bk], s1 = bs[bk + 1];
  for (int j = s0 + t; j < s1; j += 256) {
    int v = part[j];
    int s = v >> LOGD, dl = v & (DPB - 1);
    float2 av = ((const float2*)as_)[s];
    float a0 = av.x + adv[dl].x; a0 = a0 > 0.f ? a0 : 0.2f * a0;
    float a1 = av.y + adv[dl].y; a1 = a1 > 0.f ? a1 : 0.2f * a1;
    float e0 = __expf(a0), e1 = __expf(a1);
    float4 xa = ((const float4*)xps)[(size_t)s * 2];
    float4 xb = ((const float4*)xps)[(size_t)s * 2 + 1];
    float* A = &acc[dl * 11];
    atomicAdd(A + 0, e0 * xa.x); atomicAdd(A + 1, e0 * xa.y);
    atomicAdd(A + 2, e0 * xa.z); atomicAdd(A + 3, e0 * xa.w);
    atomicAdd(A + 4, e1 * xb.x); atomicAdd(A + 5, e1 * xb.y);
    atomicAdd(A + 6, e1 * xb.z); atomicAdd(A + 7, e1 * xb.w);
    atomicAdd(A + 8, e0); atomicAdd(A + 9, e1);
  }
  __syncthreads();
  for (int dl = t; dl < nd; dl += 256) {
    float* A = &acc[dl * 11];
    float r0 = 1.f / (A[8] + 1e-16f), r1 = 1.f / (A[9] + 1e-16f);
    float4 q0 = make_float4(fmaxf(A[0] * r0, 0.f), fmaxf(A[1] * r0, 0.f),
                            fmaxf(A[2] * r0, 0.f), fmaxf(A[3] * r0, 0.f));
    float4 q1 = make_float4(fmaxf(A[4] * r1, 0.f), fmaxf(A[5] * r1, 0.f),
                            fmaxf(A[6] * r1, 0.f), fmaxf(A[7] * r1, 0.f));
    ((float4*)out)[(size_t)(d0 + dl) * 2] = q0;
    ((float4*)out)[(size_t)(d0 + dl) * 2 + 1] = q1;
  }
}

// ---------------- layer-2 per-bucket softmax-aggregate (H=1, F=7) ----------------
__global__ __launch_bounds__(256) void k_aggr2(
    const int* __restrict__ PART, const int* __restrict__ BSTART, int NBmax, int E,
    int ti0, int ti1,
    const float* __restrict__ as0, const float* __restrict__ ad0,
    const float* __restrict__ x0, float* __restrict__ o0,
    const float* __restrict__ as1, const float* __restrict__ ad1,
    const float* __restrict__ x1, float* __restrict__ o1, int N)
{
  int zz = blockIdx.y;
  int ty = zz == 0 ? ti0 : ti1;
  const float* as_ = zz == 0 ? as0 : as1;
  const float* ad_ = zz == 0 ? ad0 : ad1;
  const float* xps = zz == 0 ? x0 : x1;
  float* out = zz == 0 ? o0 : o1;
  const int* part = PART + (size_t)ty * E;
  int bk = blockIdx.x;
  int d0 = bk << LOGD;
  if (d0 >= N) return;
  int nd = min(DPB, N - d0);
  __shared__ float acc[DPB * 9];           // 7 acc + 1 denom, stride 9
  __shared__ float adv[DPB];
  int t = threadIdx.x;
  for (int i = t; i < DPB * 9; i += 256) acc[i] = 0.f;
  for (int i = t; i < nd; i += 256) adv[i] = ad_[d0 + i];
  __syncthreads();
  const int* bs = BSTART + (size_t)ty * (NBmax + 1);
  int s0 = bs[bk], s1 = bs[bk + 1];
  for (int j = s0 + t; j < s1; j += 256) {
    int v = part[j];
    int s = v >> LOGD, dl = v & (DPB - 1);
    float a = as_[s] + adv[dl]; a = a > 0.f ? a : 0.2f * a;
    float ex = __expf(a);
    float4 xa = ((const float4*)xps)[(size_t)s * 2];
    float4 xb = ((const float4*)xps)[(size_t)s * 2 + 1];
    float* A = &acc[dl * 9];
    atomicAdd(A + 0, ex * xa.x); atomicAdd(A + 1, ex * xa.y);
    atomicAdd(A + 2, ex * xa.z); atomicAdd(A + 3, ex * xa.w);
    atomicAdd(A + 4, ex * xb.x); atomicAdd(A + 5, ex * xb.y);
    atomicAdd(A + 6, ex * xb.z); atomicAdd(A + 7, ex);
  }
  __syncthreads();
  for (int dl = t; dl < nd; dl += 256) {
    float* A = &acc[dl * 9];
    float r = 1.f / (A[7] + 1e-16f);
    float4 q0 = make_float4(fmaxf(A[0] * r, 0.f), fmaxf(A[1] * r, 0.f),
                            fmaxf(A[2] * r, 0.f), fmaxf(A[3] * r, 0.f));
    float4 q1 = make_float4(fmaxf(A[4] * r, 0.f), fmaxf(A[5] * r, 0.f),
                            fmaxf(A[6] * r, 0.f), 0.f);
    ((float4*)out)[(size_t)(d0 + dl) * 2] = q0;
    ((float4*)out)[(size_t)(d0 + dl) * 2 + 1] = q1;
  }
}

// ---------------- semantic-attention reduction ----------------
__global__ __launch_bounds__(256) void k_red(
    const float* __restrict__ h, int N, int F,
    const float* __restrict__ kw, const float* __restrict__ kb,
    float* __restrict__ red)
{
  __shared__ float kws[64], kbs[8];
  __shared__ float sm[256 * 8];
  int t = threadIdx.x;
  if (t < F * F) kws[t] = kw[t];
  if (t < F) kbs[t] = kb[t];
  __syncthreads();
  float acc[8] = {0, 0, 0, 0, 0, 0, 0, 0};
  for (int n = blockIdx.x * 256 + t; n < N; n += gridDim.x * 256) {
    const float* row = h + (size_t)n * 8;
    float xv[8];
    for (int k = 0; k < F; k++) xv[k] = row[k];
    for (int f = 0; f < F; f++) {
      float s = kbs[f];
      for (int k = 0; k < F; k++) s += xv[k] * kws[k * F + f];
      acc[f] += tanhf(s);
    }
  }
  for (int f = 0; f < 8; f++) sm[t * 8 + f] = (f < F) ? acc[f] : 0.f;
  __syncthreads();
  for (int s2 = 128; s2 > 0; s2 >>= 1) {
    if (t < s2)
      for (int f = 0; f < 8; f++) sm[t * 8 + f] += sm[(t + s2) * 8 + f];
    __syncthreads();
  }
  if (t < F) atomicAdd(&red[t], sm[t]);
}

// ---------------- semantic attention weights (tiny) ----------------
__global__ void k_attn(const float* __restrict__ red, const float* __restrict__ q,
                       int T, int F, float invN, float* __restrict__ attn)
{
  if (threadIdx.x != 0 || blockIdx.x != 0) return;
  float v[4]; float m = -1e30f;
  for (int t2 = 0; t2 < T; t2++) {
    float s = 0.f;
    for (int f = 0; f < F; f++) s += q[f] * red[t2 * F + f];
    s *= invN;
    v[t2] = s; m = fmaxf(m, s);
  }
  float sum = 0.f;
  for (int t2 = 0; t2 < T; t2++) { v[t2] = __expf(v[t2] - m); sum += v[t2]; }
  for (int t2 = 0; t2 < T; t2++) attn[t2] = v[t2] / sum;
}

// ---------- layer-2 projection with fused semantic combine (+relu) + fused alpha2 ----------
__global__ __launch_bounds__(256) void k_proj2(
    const float* __restrict__ h0, const float* __restrict__ h1,
    const float* __restrict__ attn, int N,
    const float* __restrict__ w, const float* __restrict__ b,
    float* __restrict__ xp2,
    const float* __restrict__ pa0, float* __restrict__ oa0,
    const float* __restrict__ pa1, float* __restrict__ oa1,
    const float* __restrict__ pa2, float* __restrict__ oa2)
{
  int n = blockIdx.x * blockDim.x + threadIdx.x;
  if (n >= N) return;
  float a0 = 1.f, a1 = 0.f;
  if (attn) { a0 = attn[0]; a1 = attn[1]; }
  float4 u0 = ((const float4*)h0)[(size_t)n * 2];
  float4 u1 = ((const float4*)h0)[(size_t)n * 2 + 1];
  float xv[8] = {u0.x, u0.y, u0.z, u0.w, u1.x, u1.y, u1.z, u1.w};
  if (h1) {
    float4 v0 = ((const float4*)h1)[(size_t)n * 2];
    float4 v1 = ((const float4*)h1)[(size_t)n * 2 + 1];
    float yv[8] = {v0.x, v0.y, v0.z, v0.w, v1.x, v1.y, v1.z, v1.w};
    for (int j = 0; j < 8; j++) xv[j] = a0 * xv[j] + a1 * yv[j];
  }
  for (int j = 0; j < 8; j++) xv[j] = fmaxf(xv[j], 0.f);
  float y[7];
  for (int j = 0; j < 7; j++) y[j] = b[j];
  for (int k = 0; k < 8; k++) {
    float xk = xv[k];
    for (int j = 0; j < 7; j++) y[j] += xk * w[k * 7 + j];
  }
  ((float4*)xp2)[(size_t)n * 2] = make_float4(y[0], y[1], y[2], y[3]);
  ((float4*)xp2)[(size_t)n * 2 + 1] = make_float4(y[4], y[5], y[6], 0.f);
#define DOA2(p, o)                                      \
  if (p) {                                              \
    float s = 0.f;                                      \
    for (int j = 0; j < 7; j++) s += y[j] * p[j];       \
    o[n] = s;                                           \
  }
  DOA2(pa0, oa0) DOA2(pa1, oa1) DOA2(pa2, oa2)
#undef DOA2
}

// ---------------- final combine + log_softmax ----------------
__global__ __launch_bounds__(256) void k_final(
    const float* __restrict__ h0, const float* __restrict__ h1,
    const float* __restrict__ attn, float* __restrict__ out, int N)
{
  int n = blockIdx.x * blockDim.x + threadIdx.x;
  if (n >= N) return;
  float a0 = attn[0], a1 = attn[1];
  const float* r0 = h0 + (size_t)n * 8;
  const float* r1 = h1 + (size_t)n * 8;
  float v[7]; float m = -1e30f;
  for (int c = 0; c < 7; c++) { float t = a0 * r0[c] + a1 * r1[c]; v[c] = t; m = fmaxf(m, t); }
  float sum = 0.f;
  for (int c = 0; c < 7; c++) sum += __expf(v[c] - m);
  float lse = m + logf(sum);
  for (int c = 0; c < 7; c++) out[(size_t)n * 7 + c] = v[c] - lse;
}

extern "C" void kernel_launch(void* const* d_in, const int* in_sizes, int n_in,
                              void* d_out, int out_size, void* d_ws, size_t ws_size,
                              hipStream_t stream)
{
  const float* x_p  = (const float*)d_in[0];
  const float* x_a  = (const float*)d_in[1];
  const int*   eipp = (const int*)d_in[2];
  const int*   eipa = (const int*)d_in[3];
  const int*   eiap = (const int*)d_in[4];
  const float* w1p  = (const float*)d_in[5];
  const float* b1p  = (const float*)d_in[6];
  const float* w1a  = (const float*)d_in[7];
  const float* b1a  = (const float*)d_in[8];
  const float* as1pp = (const float*)d_in[9];
  const float* ad1pp = (const float*)d_in[10];
  const float* as1pa = (const float*)d_in[11];
  const float* ad1pa = (const float*)d_in[12];
  const float* as1ap = (const float*)d_in[13];
  const float* ad1ap = (const float*)d_in[14];
  const float* kw1 = (const float*)d_in[15];
  const float* kb1 = (const float*)d_in[16];
  const float* q1  = (const float*)d_in[17];
  const float* w2p = (const float*)d_in[18];
  const float* b2p = (const float*)d_in[19];
  const float* w2a = (const float*)d_in[20];
  const float* b2a = (const float*)d_in[21];
  const float* as2pp = (const float*)d_in[22];
  const float* ad2pp = (const float*)d_in[23];
  // d_in[24]=as2pa, d_in[25]=ad2pa unused: pa edges only feed author nodes,
  // and author layer-2 output is dead (final output is papers only).
  const float* as2ap = (const float*)d_in[26];
  const float* ad2ap = (const float*)d_in[27];
  const float* kw2 = (const float*)d_in[28];
  const float* kb2 = (const float*)d_in[29];
  const float* q2  = (const float*)d_in[30];

  const int NP = in_sizes[0] / DIN;
  const int NA = in_sizes[1] / DIN;
  const int E  = in_sizes[2] / 2;
  (void)n_in; (void)out_size; (void)ws_size;

  const int nblocks = (E + BE - 1) / BE;
  const int NBp = (NP + DPB - 1) >> LOGD;
  const int NBa = (NA + DPB - 1) >> LOGD;
  const int NBmax = NBp > NBa ? NBp : NBa;

  float* w = (float*)d_ws;
  size_t off_ = 0;
  auto A = [&](size_t n) { float* p = w + off_; off_ += (n + 3) & ~(size_t)3; return p; };
  float* XP_P1 = A((size_t)NP * 8);   // reused as XP2_P
  float* XP_A1 = A((size_t)NA * 8);   // reused as XP2_A
  float* AS_PP = A((size_t)NP * 2);   // reused as A2SPP
  float* AD_PP = A((size_t)NP * 2);   // reused as A2DPP
  float* AS_PA = A((size_t)NP * 2);   // reused as A2DAP
  float* AD_PA = A((size_t)NA * 2);   // reused as A2SAP
  float* AS_AP = A((size_t)NA * 2);
  float* AD_AP = A((size_t)NP * 2);
  float* O_PP  = A((size_t)NP * 8);   // reused as O2PP
  float* O_PA  = A((size_t)NA * 8);
  float* O_AP  = A((size_t)NP * 8);   // reused as O2AP
  float* ATT1  = A(2);
  float* ATT2  = A(2);
  float* RED1  = A(16);
  float* RED2  = A(16);
  int* PART   = (int*)A((size_t)3 * E);                    // per-type regions PART + ty*E
  int* PB1    = (int*)A((size_t)3 * NBCAP * nblocks);      // row stride NBCAP
  int* TOTS   = (int*)A((size_t)3 * NBmax);
  int* BSTART = (int*)A((size_t)3 * (NBmax + 1));

  float* XP2_P = XP_P1;
  float* XP2_A = XP_A1;
  float* A2SPP = AS_PP;
  float* A2DPP = AD_PP;
  float* A2DAP = AS_PA;
  float* A2SAP = AD_PA;
  float* O2PP  = O_PP;
  float* O2AP  = O_AP;

  hipMemsetAsync(RED1, 0, 32 * sizeof(float), stream);  // RED1+RED2 contiguous

  dim3 B(256);
  int nbP = (NP + 255) / 256, nbA = (NA + 255) / 256;

  // layer 1 projections + per-node alphas
  k_proj1<<<(NP + 31) / 32, B, 0, stream>>>(x_p, w1p, b1p, XP_P1, NP);
  k_proj1<<<(NA + 31) / 32, B, 0, stream>>>(x_a, w1a, b1a, XP_A1, NA);
  k_alpha1<<<nbP, B, 0, stream>>>(XP_P1, NP,
      as1pp, AS_PP, ad1pp, AD_PP, as1pa, AS_PA, ad1ap, AD_AP);
  k_alpha1<<<nbA, B, 0, stream>>>(XP_A1, NA,
      ad1pa, AD_PA, as1ap, AS_AP, nullptr, nullptr, nullptr, nullptr);

  // bucket partition for all 3 edge types (type order: pp, pa, ap; bucket = dst >> 8)
  k_bcount<<<dim3(nblocks, 3), dim3(512), 0, stream>>>(
      eipp + E, eipa + E, eiap + E, E, nblocks, PB1);
  k_bscan<<<dim3(NBmax, 3), dim3(512), 0, stream>>>(
      PB1, TOTS, nblocks, NBmax, NBp, NBa, NBp);
  k_bstart<<<3, dim3(512), 0, stream>>>(TOTS, BSTART, NBmax, NBp, NBa, NBp);
  k_bplace<<<dim3(nblocks, 3), dim3(512), 0, stream>>>(
      eipp, eipa, eiap, E, nblocks, NBmax, NBp, NBa, NBp, PB1, BSTART, PART);

  // layer-1 per-bucket aggregation (all 3 types)
  k_aggr1<<<dim3(NBmax, 3), B, 0, stream>>>(
      PART, BSTART, NBmax, E,
      AS_PP, AD_PP, XP_P1, O_PP, NP,
      AS_PA, AD_PA, XP_P1, O_PA, NA,
      AS_AP, AD_AP, XP_A1, O_AP, NP);

  // layer 1 semantic attention (paper: T=2; author: T=1 -> O_PA passes through)
  k_red<<<256, B, 0, stream>>>(O_PP, NP, 8, kw1, kb1, RED1);
  k_red<<<256, B, 0, stream>>>(O_AP, NP, 8, kw1, kb1, RED1 + 8);
  k_attn<<<1, 1, 0, stream>>>(RED1, q1, 2, 8, 1.0f / NP, ATT1);

  // layer 2 projections (paper: fused semantic combine; author: passthrough) + alphas
  k_proj2<<<nbP, B, 0, stream>>>(O_PP, O_AP, ATT1, NP, w2p, b2p, XP2_P,
      as2pp, A2SPP, ad2pp, A2DPP, ad2ap, A2DAP);
  k_proj2<<<nbA, B, 0, stream>>>(O_PA, nullptr, nullptr, NA, w2a, b2a, XP2_A,
      as2ap, A2SAP, nullptr, nullptr, nullptr, nullptr);

  // layer-2 per-bucket aggregation (pp and ap; author layer-2 output is dead)
  k_aggr2<<<dim3(NBp, 2), B, 0, stream>>>(
      PART, BSTART, NBmax, E, 0, 2,
      A2SPP, A2DPP, XP2_P, O2PP,
      A2SAP, A2DAP, XP2_A, O2AP, NP);

  // layer 2 semantic attention + final log_softmax
  k_red<<<256, B, 0, stream>>>(O2PP, NP, 7, kw2, kb2, RED2);
  k_red<<<256, B, 0, stream>>>(O2AP, NP, 7, kw2, kb2, RED2 + 7);
  k_attn<<<1, 1, 0, stream>>>(RED2, q2, 2, 7, 1.0f / NP, ATT2);
  k_final<<<nbP, B, 0, stream>>>(O2PP, O2AP, ATT2, (float*)d_out, NP);
}